// Round 3
// baseline (1993.419 us; speedup 1.0000x reference)
//
#include <hip/hip_runtime.h>
#include <hip/hip_bf16.h>
#include <math.h>

#define N_PTS 8192
#define QPB 4            // queries per block = waves per block
#define GRID 24
#define NC (GRID * GRID * GRID)   // 13824 cells
#define CELL_H 0.5f
#define INV_H 2.0f
#define MINB -6.0f
#define RMAX 2           // rings tried before brute-force fallback

// F_CHAMFER*ALPHA0 = 0.02, F_CURVATURE*ALPHA0 = 0.006, F_SMOOTH*ALPHA0 = 0.01
#define W_CHAM 0.02f
#define W_CURV 0.006f
#define W_SMOO 0.01f

#define BIGF 1e30f

__device__ __forceinline__ int cell1(float x) {
    int c = (int)floorf((x - MINB) * INV_H);
    return min(max(c, 0), GRID - 1);
}

// ---- wave-uniform sorted insert (args identical across lanes; predicated chain) ----
template <int K>
__device__ __forceinline__ void uinsert(float d, int idx, float (&bd)[K], int (&bi)[K]) {
    bd[K - 1] = d; bi[K - 1] = idx;
#pragma unroll
    for (int s = K - 1; s > 0; --s) {
        bool sw = bd[s] < bd[s - 1];
        float td = sw ? bd[s - 1] : bd[s];
        bd[s - 1] = sw ? bd[s] : bd[s - 1];
        bd[s] = td;
        int ti = sw ? bi[s - 1] : bi[s];
        bi[s - 1] = sw ? bi[s] : bi[s - 1];
        bi[s] = ti;
    }
}

// ---- exact grid kNN for one wave-uniform query ----
template <int K>
__device__ void grid_knn(float qx, float qy, float qz,
                         const float* __restrict__ spx, const float* __restrict__ spy,
                         const float* __restrict__ spz, const int* __restrict__ sidx,
                         const int* __restrict__ starts, const int* __restrict__ counts,
                         float (&bd)[K], int (&bi)[K], int lane) {
#pragma unroll
    for (int r = 0; r < K; ++r) { bd[r] = BIGF; bi[r] = 0; }
    const int cx = cell1(qx), cy = cell1(qy), cz = cell1(qz);

    auto chunks = [&](int s0, int n) {
        for (int base = 0; base < n; base += 64) {
            int j = base + lane;
            float d = BIGF; int idx = 0;
            if (j < n) {
                float dx = spx[s0 + j] - qx;
                float dy = spy[s0 + j] - qy;
                float dz = spz[s0 + j] - qz;
                d = dx * dx + dy * dy + dz * dz;
                idx = sidx[s0 + j];
            }
            unsigned long long m = __ballot(d < bd[K - 1]);
            while (m) {
                int b = __builtin_ctzll(m);
                m &= m - 1;
                float dv = __shfl(d, b);
                int   iv = __shfl(idx, b);
                if (dv < bd[K - 1]) uinsert<K>(dv, iv, bd, bi);
            }
        }
    };

    bool done = false;
    for (int r = 0; r <= RMAX; ++r) {
        const int zlo = max(cz - r, 0), zhi = min(cz + r, GRID - 1);
        const int ylo = max(cy - r, 0), yhi = min(cy + r, GRID - 1);
        const int xlo = max(cx - r, 0), xhi = min(cx + r, GRID - 1);
        for (int z = zlo; z <= zhi; ++z) {
            int az = abs(z - cz);
            for (int y = ylo; y <= yhi; ++y) {
                int ay = max(az, abs(y - cy));
                if (ay == r) {
                    for (int x = xlo; x <= xhi; ++x) {
                        int c = (z * GRID + y) * GRID + x;
                        chunks(starts[c], counts[c]);
                    }
                } else {
                    int x = cx - r;
                    if (x >= 0) { int c = (z * GRID + y) * GRID + x; chunks(starts[c], counts[c]); }
                    x = cx + r;
                    if (r > 0 && x <= GRID - 1) { int c = (z * GRID + y) * GRID + x; chunks(starts[c], counts[c]); }
                }
            }
        }
        // exact stop rule: min distance from q (true position) to any unexamined cell
        float R = 1e18f;
        if (cx - r > 0)        R = fminf(R, qx - (MINB + (float)(cx - r) * CELL_H));
        if (cx + r < GRID - 1) R = fminf(R, (MINB + (float)(cx + r + 1) * CELL_H) - qx);
        if (cy - r > 0)        R = fminf(R, qy - (MINB + (float)(cy - r) * CELL_H));
        if (cy + r < GRID - 1) R = fminf(R, (MINB + (float)(cy + r + 1) * CELL_H) - qy);
        if (cz - r > 0)        R = fminf(R, qz - (MINB + (float)(cz - r) * CELL_H));
        if (cz + r < GRID - 1) R = fminf(R, (MINB + (float)(cz + r + 1) * CELL_H) - qz);
        if (R >= 0.0f && bd[K - 1] <= R * R) { done = true; break; }
    }
    if (!done) {
        // sparse-tail fallback: reset and brute-scan everything (exact, no duplicates)
#pragma unroll
        for (int r = 0; r < K; ++r) { bd[r] = BIGF; bi[r] = 0; }
        chunks(0, N_PTS);
    }
}

// ---- kernel 0: pc2 = coords+gt, warp = coords+flow, zero counts + accs ----
__global__ void prep_kernel(const float* __restrict__ flow, const float* __restrict__ gt,
                            const float* __restrict__ coords,
                            float* __restrict__ pc2, float* __restrict__ warp,
                            int* __restrict__ counts, float* __restrict__ accs) {
    int i = blockIdx.x * blockDim.x + threadIdx.x;
    if (i < N_PTS * 3) {
        float c = coords[i];
        pc2[i]  = c + gt[i];
        warp[i] = c + flow[i];
    }
    if (i < 3 * NC) counts[i] = 0;
    if (i < 8) accs[i] = 0.0f;
}

// ---- binning: count ----
__global__ void count_kernel(const float* __restrict__ coords, const float* __restrict__ pc2,
                             const float* __restrict__ warp, int* __restrict__ counts) {
    int i = blockIdx.x * blockDim.x + threadIdx.x;
    if (i >= 3 * N_PTS) return;
    int s = i / N_PTS, j = i - s * N_PTS;
    const float* src = (s == 0) ? coords : ((s == 1) ? pc2 : warp);
    int c = (cell1(src[j * 3 + 2]) * GRID + cell1(src[j * 3 + 1])) * GRID + cell1(src[j * 3 + 0]);
    atomicAdd(&counts[s * NC + c], 1);
}

// ---- binning: exclusive scan per set (one block per set) ----
__global__ __launch_bounds__(256) void scan_kernel(const int* __restrict__ counts,
                                                   int* __restrict__ starts,
                                                   int* __restrict__ cursor) {
    const int s = blockIdx.x;
    const int t = threadIdx.x;
    const int CPT = NC / 256;  // 54
    const int* cnt = counts + s * NC;
    int* st = starts + s * NC;
    int* cu = cursor + s * NC;
    int local = 0;
    const int base0 = t * CPT;
    for (int i = 0; i < CPT; ++i) local += cnt[base0 + i];
    __shared__ int sdata[256];
    sdata[t] = local;
    __syncthreads();
    for (int off = 1; off < 256; off <<= 1) {
        int v = (t >= off) ? sdata[t - off] : 0;
        __syncthreads();
        sdata[t] += v;
        __syncthreads();
    }
    int run = sdata[t] - local;  // exclusive prefix
    for (int i = 0; i < CPT; ++i) {
        int c = base0 + i;
        st[c] = run; cu[c] = run;
        run += cnt[c];
    }
}

// ---- binning: scatter into SoA sorted-by-cell arrays ----
__global__ void scatter_kernel(const float* __restrict__ coords, const float* __restrict__ pc2,
                               const float* __restrict__ warp, int* __restrict__ cursor,
                               float* __restrict__ spx, float* __restrict__ spy,
                               float* __restrict__ spz, int* __restrict__ sidx) {
    int i = blockIdx.x * blockDim.x + threadIdx.x;
    if (i >= 3 * N_PTS) return;
    int s = i / N_PTS, j = i - s * N_PTS;
    const float* src = (s == 0) ? coords : ((s == 1) ? pc2 : warp);
    float x = src[j * 3 + 0], y = src[j * 3 + 1], z = src[j * 3 + 2];
    int c = (cell1(z) * GRID + cell1(y)) * GRID + cell1(x);
    int pos = atomicAdd(&cursor[s * NC + c], 1);
    int o = s * N_PTS + pos;
    spx[o] = x; spy[o] = y; spz[o] = z; sidx[o] = j;
}

// ---- kernel: curvature of pc2 via grid-kNN(pc2,pc2,10) ----
__global__ __launch_bounds__(256) void curv2_kernel(const float* __restrict__ pc2,
                                                    const float* __restrict__ spx, const float* __restrict__ spy,
                                                    const float* __restrict__ spz, const int* __restrict__ sidx,
                                                    const int* __restrict__ starts, const int* __restrict__ counts,
                                                    float* __restrict__ curv2) {
    const int tid = threadIdx.x, lane = tid & 63, wv = tid >> 6;
    const int q = blockIdx.x * QPB + wv;
    const float qx = pc2[q * 3 + 0], qy = pc2[q * 3 + 1], qz = pc2[q * 3 + 2];
    constexpr int K = 10;
    float bd[K]; int bi[K];
    grid_knn<K>(qx, qy, qz, spx, spy, spz, sidx, starts, counts, bd, bi, lane);
    float ax = 0.f, ay = 0.f, az = 0.f;
#pragma unroll
    for (int r = 0; r < K; ++r) {
        ax += pc2[bi[r] * 3 + 0];
        ay += pc2[bi[r] * 3 + 1];
        az += pc2[bi[r] * 3 + 2];
    }
    if (lane == 0) {
        curv2[q * 3 + 0] = (ax - 10.f * qx) * (1.f / 9.f);
        curv2[q * 3 + 1] = (ay - 10.f * qy) * (1.f / 9.f);
        curv2[q * 3 + 2] = (az - 10.f * qz) * (1.f / 9.f);
    }
}

// ---- kernel: grid-kNN(pc1,pc1,10) -> moved_curv + smoothness ----
__global__ __launch_bounds__(256) void pc1_kernel(const float* __restrict__ coords,
                                                  const float* __restrict__ warp,
                                                  const float* __restrict__ flow,
                                                  const int* __restrict__ ksm_p,
                                                  const float* __restrict__ spx, const float* __restrict__ spy,
                                                  const float* __restrict__ spz, const int* __restrict__ sidx,
                                                  const int* __restrict__ starts, const int* __restrict__ counts,
                                                  float* __restrict__ mcurv, float* __restrict__ accs) {
    __shared__ float psm[QPB];
    const int tid = threadIdx.x, lane = tid & 63, wv = tid >> 6;
    const int q = blockIdx.x * QPB + wv;
    const float qx = coords[q * 3 + 0], qy = coords[q * 3 + 1], qz = coords[q * 3 + 2];
    constexpr int K = 10;
    float bd[K]; int bi[K];
    grid_knn<K>(qx, qy, qz, spx, spy, spz, sidx, starts, counts, bd, bi, lane);

    const float wqx = warp[q * 3 + 0], wqy = warp[q * 3 + 1], wqz = warp[q * 3 + 2];
    const float fqx = flow[q * 3 + 0], fqy = flow[q * 3 + 1], fqz = flow[q * 3 + 2];
    const int ksm = ksm_p[0];  // 9
    float ax = 0.f, ay = 0.f, az = 0.f, sm = 0.f;
#pragma unroll
    for (int r = 0; r < K; ++r) {
        ax += warp[bi[r] * 3 + 0];
        ay += warp[bi[r] * 3 + 1];
        az += warp[bi[r] * 3 + 2];
        if (r < ksm) {
            float dx = flow[bi[r] * 3 + 0] - fqx;
            float dy = flow[bi[r] * 3 + 1] - fqy;
            float dz = flow[bi[r] * 3 + 2] - fqz;
            float sq = dx * dx + dy * dy + dz * dz;
            sm += (sq == 0.f) ? 0.f : sqrtf(sq);
        }
    }
    if (lane == 0) {
        mcurv[q * 3 + 0] = (ax - 10.f * wqx) * (1.f / 9.f);
        mcurv[q * 3 + 1] = (ay - 10.f * wqy) * (1.f / 9.f);
        mcurv[q * 3 + 2] = (az - 10.f * wqz) * (1.f / 9.f);
        psm[wv] = sm * 0.125f;  // /8.0 hard-coded in reference
    }
    __syncthreads();
    if (tid == 0) atomicAdd(&accs[2], psm[0] + psm[1] + psm[2] + psm[3]);
}

// ---- kernel: grid-kNN(warp->pc2,5) -> chamfer dist1 + curvature-interp loss ----
__global__ __launch_bounds__(256) void cross_kernel(const float* __restrict__ warp,
                                                    const float* __restrict__ curv2,
                                                    const float* __restrict__ mcurv,
                                                    const float* __restrict__ spx, const float* __restrict__ spy,
                                                    const float* __restrict__ spz, const int* __restrict__ sidx,
                                                    const int* __restrict__ starts, const int* __restrict__ counts,
                                                    float* __restrict__ accs) {
    __shared__ float pc1s[QPB], pcvs[QPB];
    const int tid = threadIdx.x, lane = tid & 63, wv = tid >> 6;
    const int q = blockIdx.x * QPB + wv;
    const float qx = warp[q * 3 + 0], qy = warp[q * 3 + 1], qz = warp[q * 3 + 2];
    constexpr int K = 5;
    float bd[K]; int bi[K];
    grid_knn<K>(qx, qy, qz, spx, spy, spz, sidx, starts, counts, bd, bi, lane);

    float w[K], wsum = 0.f;
#pragma unroll
    for (int r = 0; r < K; ++r) { w[r] = 1.f / (bd[r] + 1e-8f); wsum += w[r]; }
    float ix = 0.f, iy = 0.f, iz = 0.f;
#pragma unroll
    for (int r = 0; r < K; ++r) {
        float ww = w[r] / wsum;
        ix += ww * curv2[bi[r] * 3 + 0];
        iy += ww * curv2[bi[r] * 3 + 1];
        iz += ww * curv2[bi[r] * 3 + 2];
    }
    float dx = ix - mcurv[q * 3 + 0];
    float dy = iy - mcurv[q * 3 + 1];
    float dz = iz - mcurv[q * 3 + 2];
    if (lane == 0) {
        pc1s[wv] = bd[0];                       // dist1 (min)
        pcvs[wv] = dx * dx + dy * dy + dz * dz; // curvature term
    }
    __syncthreads();
    if (tid == 0) {
        atomicAdd(&accs[0], pc1s[0] + pc1s[1] + pc1s[2] + pc1s[3]);
        atomicAdd(&accs[3], pcvs[0] + pcvs[1] + pcvs[2] + pcvs[3]);
    }
}

// ---- kernel: reverse chamfer: 1-NN of each pc2 point in warp-grid ----
__global__ __launch_bounds__(256) void rev_kernel(const float* __restrict__ pc2,
                                                  const float* __restrict__ spx, const float* __restrict__ spy,
                                                  const float* __restrict__ spz,
                                                  const int* __restrict__ starts, const int* __restrict__ counts,
                                                  float* __restrict__ accs) {
    __shared__ float pmn[QPB];
    const int tid = threadIdx.x, lane = tid & 63, wv = tid >> 6;
    const int q = blockIdx.x * QPB + wv;
    const float qx = pc2[q * 3 + 0], qy = pc2[q * 3 + 1], qz = pc2[q * 3 + 2];
    const int cx = cell1(qx), cy = cell1(qy), cz = cell1(qz);
    float mn = BIGF;

    auto chunks = [&](int s0, int n) {
        for (int base = 0; base < n; base += 64) {
            int j = base + lane;
            if (j < n) {
                float dx = spx[s0 + j] - qx;
                float dy = spy[s0 + j] - qy;
                float dz = spz[s0 + j] - qz;
                mn = fminf(mn, dx * dx + dy * dy + dz * dz);
            }
        }
    };

    bool done = false;
    float best = BIGF;
    for (int r = 0; r <= RMAX; ++r) {
        const int zlo = max(cz - r, 0), zhi = min(cz + r, GRID - 1);
        const int ylo = max(cy - r, 0), yhi = min(cy + r, GRID - 1);
        const int xlo = max(cx - r, 0), xhi = min(cx + r, GRID - 1);
        for (int z = zlo; z <= zhi; ++z) {
            int az = abs(z - cz);
            for (int y = ylo; y <= yhi; ++y) {
                int ay = max(az, abs(y - cy));
                if (ay == r) {
                    for (int x = xlo; x <= xhi; ++x) {
                        int c = (z * GRID + y) * GRID + x;
                        chunks(starts[c], counts[c]);
                    }
                } else {
                    int x = cx - r;
                    if (x >= 0) { int c = (z * GRID + y) * GRID + x; chunks(starts[c], counts[c]); }
                    x = cx + r;
                    if (r > 0 && x <= GRID - 1) { int c = (z * GRID + y) * GRID + x; chunks(starts[c], counts[c]); }
                }
            }
        }
        float b = mn;
#pragma unroll
        for (int off = 1; off < 64; off <<= 1) b = fminf(b, __shfl_xor(b, off));
        float R = 1e18f;
        if (cx - r > 0)        R = fminf(R, qx - (MINB + (float)(cx - r) * CELL_H));
        if (cx + r < GRID - 1) R = fminf(R, (MINB + (float)(cx + r + 1) * CELL_H) - qx);
        if (cy - r > 0)        R = fminf(R, qy - (MINB + (float)(cy - r) * CELL_H));
        if (cy + r < GRID - 1) R = fminf(R, (MINB + (float)(cy + r + 1) * CELL_H) - qy);
        if (cz - r > 0)        R = fminf(R, qz - (MINB + (float)(cz - r) * CELL_H));
        if (cz + r < GRID - 1) R = fminf(R, (MINB + (float)(cz + r + 1) * CELL_H) - qz);
        if (R >= 0.0f && b <= R * R) { best = b; done = true; break; }
    }
    if (!done) {
        chunks(0, N_PTS);  // extra-scan is harmless for a pure min
        float b = mn;
#pragma unroll
        for (int off = 1; off < 64; off <<= 1) b = fminf(b, __shfl_xor(b, off));
        best = b;
    }
    if (lane == 0) pmn[wv] = best;
    __syncthreads();
    if (tid == 0) atomicAdd(&accs[1], pmn[0] + pmn[1] + pmn[2] + pmn[3]);
}

// ---- finalize ----
__global__ void fin_kernel(const float* __restrict__ accs, float* __restrict__ out) {
    if (threadIdx.x == 0 && blockIdx.x == 0)
        out[0] = W_CHAM * (accs[0] + accs[1]) + W_CURV * accs[3] + W_SMOO * accs[2];
}

extern "C" void kernel_launch(void* const* d_in, const int* in_sizes, int n_in,
                              void* d_out, int out_size, void* d_ws, size_t ws_size,
                              hipStream_t stream) {
    const float* flow   = (const float*)d_in[0];  // registration_pred (1,N,3)
    const float* gt     = (const float*)d_in[1];  // registration_gt   (1,N,3)
    const float* coords = (const float*)d_in[2];  // (N,3)
    const int*   ksm    = (const int*)d_in[3];    // smoothness_k (=9)

    float* ws    = (float*)d_ws;
    float* pc2   = ws;                       // 3N
    float* warp  = ws + 3 * N_PTS;           // 3N
    float* curv2 = ws + 6 * N_PTS;           // 3N
    float* mcurv = ws + 9 * N_PTS;           // 3N
    float* accs  = ws + 12 * N_PTS;          // 8
    float* spx   = ws + 12 * N_PTS + 8;      // 3N (3 sets x N)
    float* spy   = spx + 3 * N_PTS;          // 3N
    float* spz   = spy + 3 * N_PTS;          // 3N
    int*   sidx  = (int*)(spz + 3 * N_PTS);  // 3N ints
    int*   counts = sidx + 3 * N_PTS;        // 3*NC
    int*   starts = counts + 3 * NC;         // 3*NC
    int*   cursor = starts + 3 * NC;         // 3*NC
    float* out   = (float*)d_out;

    // set bases: set0 = pc1(coords), set1 = pc2, set2 = warp
    prep_kernel<<<(3 * NC + 255) / 256, 256, 0, stream>>>(flow, gt, coords, pc2, warp, counts, accs);
    count_kernel<<<(3 * N_PTS + 255) / 256, 256, 0, stream>>>(coords, pc2, warp, counts);
    scan_kernel<<<3, 256, 0, stream>>>(counts, starts, cursor);
    scatter_kernel<<<(3 * N_PTS + 255) / 256, 256, 0, stream>>>(coords, pc2, warp, cursor,
                                                                spx, spy, spz, sidx);

    curv2_kernel<<<N_PTS / QPB, 256, 0, stream>>>(pc2,
        spx + N_PTS, spy + N_PTS, spz + N_PTS, sidx + N_PTS, starts + NC, counts + NC, curv2);
    pc1_kernel<<<N_PTS / QPB, 256, 0, stream>>>(coords, warp, flow, ksm,
        spx, spy, spz, sidx, starts, counts, mcurv, accs);
    cross_kernel<<<N_PTS / QPB, 256, 0, stream>>>(warp, curv2, mcurv,
        spx + N_PTS, spy + N_PTS, spz + N_PTS, sidx + N_PTS, starts + NC, counts + NC, accs);
    rev_kernel<<<N_PTS / QPB, 256, 0, stream>>>(pc2,
        spx + 2 * N_PTS, spy + 2 * N_PTS, spz + 2 * N_PTS, starts + 2 * NC, counts + 2 * NC, accs);
    fin_kernel<<<1, 64, 0, stream>>>(accs, out);
}

// Round 4
// 562.631 us; speedup vs baseline: 3.5430x; 3.5430x over previous
//
#include <hip/hip_runtime.h>
#include <hip/hip_bf16.h>
#include <math.h>

#define N_PTS 8192
#define TILE 256
#define QPB 4            // queries per block = waves per block

// F_CHAMFER*ALPHA0 = 0.02, F_CURVATURE*ALPHA0 = 0.006, F_SMOOTH*ALPHA0 = 0.01
#define W_CHAM 0.02f
#define W_CURV 0.006f
#define W_SMOO 0.01f

#define BIGF 1e30f

// ---- wave-uniform sorted insert (used only on the rare fallback path) ----
template <int K>
__device__ __forceinline__ void uinsert(float d, int idx, float (&bd)[K], int (&bi)[K]) {
    bd[K - 1] = d; bi[K - 1] = idx;
#pragma unroll
    for (int s = K - 1; s > 0; --s) {
        bool sw = bd[s] < bd[s - 1];
        float td = sw ? bd[s - 1] : bd[s];
        bd[s - 1] = sw ? bd[s] : bd[s - 1];
        bd[s] = td;
        int ti = sw ? bi[s - 1] : bi[s];
        bi[s - 1] = sw ? bi[s] : bi[s - 1];
        bi[s] = ti;
    }
}

// ---- exact top-K: branchless per-lane top-3 scan + K-round shuffle merge ----
// Result bd/bi is wave-uniform. sf: 3*TILE floats of LDS (AoS xyz tile).
template <int K>
__device__ void knn_scan(const float* __restrict__ cand,
                         float qx, float qy, float qz,
                         float (&bd)[K], int (&bi)[K],
                         float* sf, int tid, int lane) {
    float m1 = BIGF, m2 = BIGF, m3 = BIGF;
    int   i1 = 0,    i2 = 0;
    for (int t = 0; t < N_PTS / TILE; ++t) {
        __syncthreads();
        const float* src = cand + t * (3 * TILE);
        sf[tid]            = src[tid];
        sf[tid + TILE]     = src[tid + TILE];
        sf[tid + 2 * TILE] = src[tid + 2 * TILE];
        __syncthreads();
#pragma unroll
        for (int u = 0; u < TILE / 64; ++u) {
            const int cl = u * 64 + lane;
            float dx = sf[3 * cl + 0] - qx;
            float dy = sf[3 * cl + 1] - qy;
            float dz = sf[3 * cl + 2] - qz;
            float d = dx * dx + dy * dy + dz * dz;
            const int idx = t * TILE + cl;
            bool c1 = d < m1, c2 = d < m2, c3 = d < m3;
            m3 = c2 ? m2 : (c3 ? d : m3);
            m2 = c1 ? m1 : (c2 ? d : m2);
            i2 = c1 ? i1 : (c2 ? idx : i2);
            m1 = c1 ? d : m1;
            i1 = c1 ? idx : i1;
        }
    }

    // merge 64 sorted 3-lists (3rd entry has no index -> sentinel -1)
    float h0 = m1, h1 = m2, h2 = m3;
    int   j0 = i1, j1 = i2, j2 = -1;
#pragma unroll
    for (int r = 0; r < K; ++r) {
        float bv = h0; int bix = j0; int bl = lane;
#pragma unroll
        for (int off = 1; off < 64; off <<= 1) {
            float ov  = __shfl_xor(bv, off);
            int   oix = __shfl_xor(bix, off);
            int   ol  = __shfl_xor(bl, off);
            if (ov < bv || (ov == bv && ol < bl)) { bv = ov; bix = oix; bl = ol; }
        }
        bd[r] = bv; bi[r] = bix;
        if (lane == bl) { h0 = h1; j0 = j1; h1 = h2; j1 = j2; h2 = BIGF; j2 = -1; }
    }

    // certificate: every lane's unreported candidates are >= its m3.
    if (__ballot(m3 <= bd[K - 1]) != 0ull) {
        // rare exact fallback: rescan straight from global (no __syncthreads!)
#pragma unroll
        for (int r = 0; r < K; ++r) { bd[r] = BIGF; bi[r] = 0; }
        for (int base = 0; base < N_PTS; base += 64) {
            const int j = base + lane;
            float dx = cand[j * 3 + 0] - qx;
            float dy = cand[j * 3 + 1] - qy;
            float dz = cand[j * 3 + 2] - qz;
            float d = dx * dx + dy * dy + dz * dz;
            unsigned long long m = __ballot(d < bd[K - 1]);
            while (m) {
                int b = __builtin_ctzll(m);
                m &= m - 1;
                float dv = __shfl(d, b);
                if (dv < bd[K - 1]) uinsert<K>(dv, base + b, bd, bi);
            }
        }
    }
}

// ---- kernel 0: pc2 = coords+gt, warp = coords+flow, zero accumulators ----
__global__ void prep_kernel(const float* __restrict__ flow, const float* __restrict__ gt,
                            const float* __restrict__ coords,
                            float* __restrict__ pc2, float* __restrict__ warp,
                            float* __restrict__ accs) {
    int i = blockIdx.x * blockDim.x + threadIdx.x;
    if (i < N_PTS * 3) {
        float c = coords[i];
        pc2[i]  = c + gt[i];
        warp[i] = c + flow[i];
    }
    if (i < 8) accs[i] = 0.0f;
}

// ---- kernel 1: curvature of pc2 via kNN(pc2,pc2,10) ----
__global__ __launch_bounds__(256) void curv2_kernel(const float* __restrict__ pc2,
                                                    float* __restrict__ curv2) {
    __shared__ float sf[3 * TILE];
    const int tid = threadIdx.x, lane = tid & 63, wv = tid >> 6;
    const int q = blockIdx.x * QPB + wv;
    const float qx = pc2[q * 3 + 0], qy = pc2[q * 3 + 1], qz = pc2[q * 3 + 2];
    constexpr int K = 10;
    float bd[K]; int bi[K];
    knn_scan<K>(pc2, qx, qy, qz, bd, bi, sf, tid, lane);
    float ax = 0.f, ay = 0.f, az = 0.f;
#pragma unroll
    for (int r = 0; r < K; ++r) {
        ax += pc2[bi[r] * 3 + 0];
        ay += pc2[bi[r] * 3 + 1];
        az += pc2[bi[r] * 3 + 2];
    }
    if (lane == 0) {
        curv2[q * 3 + 0] = (ax - 10.f * qx) * (1.f / 9.f);
        curv2[q * 3 + 1] = (ay - 10.f * qy) * (1.f / 9.f);
        curv2[q * 3 + 2] = (az - 10.f * qz) * (1.f / 9.f);
    }
}

// ---- kernel 2: kNN(pc1,pc1,10) -> moved_curv + smoothness ----
__global__ __launch_bounds__(256) void pc1_kernel(const float* __restrict__ coords,
                                                  const float* __restrict__ warp,
                                                  const float* __restrict__ flow,
                                                  const int* __restrict__ ksm_p,
                                                  float* __restrict__ mcurv,
                                                  float* __restrict__ accs) {
    __shared__ float sf[3 * TILE];
    __shared__ float psm[QPB];
    const int tid = threadIdx.x, lane = tid & 63, wv = tid >> 6;
    const int q = blockIdx.x * QPB + wv;
    const float qx = coords[q * 3 + 0], qy = coords[q * 3 + 1], qz = coords[q * 3 + 2];
    constexpr int K = 10;
    float bd[K]; int bi[K];
    knn_scan<K>(coords, qx, qy, qz, bd, bi, sf, tid, lane);

    const float wqx = warp[q * 3 + 0], wqy = warp[q * 3 + 1], wqz = warp[q * 3 + 2];
    const float fqx = flow[q * 3 + 0], fqy = flow[q * 3 + 1], fqz = flow[q * 3 + 2];
    const int ksm = ksm_p[0];  // 9
    float ax = 0.f, ay = 0.f, az = 0.f, sm = 0.f;
#pragma unroll
    for (int r = 0; r < K; ++r) {
        ax += warp[bi[r] * 3 + 0];
        ay += warp[bi[r] * 3 + 1];
        az += warp[bi[r] * 3 + 2];
        if (r < ksm) {
            float dx = flow[bi[r] * 3 + 0] - fqx;
            float dy = flow[bi[r] * 3 + 1] - fqy;
            float dz = flow[bi[r] * 3 + 2] - fqz;
            float sq = dx * dx + dy * dy + dz * dz;
            sm += (sq == 0.f) ? 0.f : sqrtf(sq);
        }
    }
    if (lane == 0) {
        mcurv[q * 3 + 0] = (ax - 10.f * wqx) * (1.f / 9.f);
        mcurv[q * 3 + 1] = (ay - 10.f * wqy) * (1.f / 9.f);
        mcurv[q * 3 + 2] = (az - 10.f * wqz) * (1.f / 9.f);
        psm[wv] = sm * 0.125f;  // /8.0 hard-coded in reference
    }
    __syncthreads();
    if (tid == 0) atomicAdd(&accs[2], psm[0] + psm[1] + psm[2] + psm[3]);
}

// ---- kernel 3: kNN(warp->pc2,5) -> chamfer dist1 + curvature-interp loss ----
__global__ __launch_bounds__(256) void cross_kernel(const float* __restrict__ warp,
                                                    const float* __restrict__ pc2,
                                                    const float* __restrict__ curv2,
                                                    const float* __restrict__ mcurv,
                                                    float* __restrict__ accs) {
    __shared__ float sf[3 * TILE];
    __shared__ float pc1s[QPB], pcvs[QPB];
    const int tid = threadIdx.x, lane = tid & 63, wv = tid >> 6;
    const int q = blockIdx.x * QPB + wv;
    const float qx = warp[q * 3 + 0], qy = warp[q * 3 + 1], qz = warp[q * 3 + 2];
    constexpr int K = 5;
    float bd[K]; int bi[K];
    knn_scan<K>(pc2, qx, qy, qz, bd, bi, sf, tid, lane);

    float w[K], wsum = 0.f;
#pragma unroll
    for (int r = 0; r < K; ++r) { w[r] = 1.f / (bd[r] + 1e-8f); wsum += w[r]; }
    float ix = 0.f, iy = 0.f, iz = 0.f;
#pragma unroll
    for (int r = 0; r < K; ++r) {
        float ww = w[r] / wsum;
        ix += ww * curv2[bi[r] * 3 + 0];
        iy += ww * curv2[bi[r] * 3 + 1];
        iz += ww * curv2[bi[r] * 3 + 2];
    }
    float dx = ix - mcurv[q * 3 + 0];
    float dy = iy - mcurv[q * 3 + 1];
    float dz = iz - mcurv[q * 3 + 2];
    if (lane == 0) {
        pc1s[wv] = bd[0];                       // dist1 (min)
        pcvs[wv] = dx * dx + dy * dy + dz * dz; // curvature term
    }
    __syncthreads();
    if (tid == 0) {
        atomicAdd(&accs[0], pc1s[0] + pc1s[1] + pc1s[2] + pc1s[3]);
        atomicAdd(&accs[3], pcvs[0] + pcvs[1] + pcvs[2] + pcvs[3]);
    }
}

// ---- kernel 4: reverse chamfer: min over warp for each pc2 point ----
__global__ __launch_bounds__(256) void rev_kernel(const float* __restrict__ pc2,
                                                  const float* __restrict__ warp,
                                                  float* __restrict__ accs) {
    __shared__ float sf[3 * TILE];
    __shared__ float pmn[QPB];
    const int tid = threadIdx.x, lane = tid & 63, wv = tid >> 6;
    const int q = blockIdx.x * QPB + wv;
    const float qx = pc2[q * 3 + 0], qy = pc2[q * 3 + 1], qz = pc2[q * 3 + 2];
    float mny = BIGF;
    for (int t = 0; t < N_PTS / TILE; ++t) {
        __syncthreads();
        const float* src = warp + t * (3 * TILE);
        sf[tid]            = src[tid];
        sf[tid + TILE]     = src[tid + TILE];
        sf[tid + 2 * TILE] = src[tid + 2 * TILE];
        __syncthreads();
#pragma unroll
        for (int u = 0; u < TILE / 64; ++u) {
            const int cl = u * 64 + lane;
            float dx = sf[3 * cl + 0] - qx;
            float dy = sf[3 * cl + 1] - qy;
            float dz = sf[3 * cl + 2] - qz;
            mny = fminf(mny, dx * dx + dy * dy + dz * dz);
        }
    }
#pragma unroll
    for (int off = 1; off < 64; off <<= 1) mny = fminf(mny, __shfl_xor(mny, off));
    if (lane == 0) pmn[wv] = mny;
    __syncthreads();
    if (tid == 0) atomicAdd(&accs[1], pmn[0] + pmn[1] + pmn[2] + pmn[3]);
}

// ---- kernel 5: finalize ----
__global__ void fin_kernel(const float* __restrict__ accs, float* __restrict__ out) {
    if (threadIdx.x == 0 && blockIdx.x == 0)
        out[0] = W_CHAM * (accs[0] + accs[1]) + W_CURV * accs[3] + W_SMOO * accs[2];
}

extern "C" void kernel_launch(void* const* d_in, const int* in_sizes, int n_in,
                              void* d_out, int out_size, void* d_ws, size_t ws_size,
                              hipStream_t stream) {
    const float* flow   = (const float*)d_in[0];  // registration_pred (1,N,3)
    const float* gt     = (const float*)d_in[1];  // registration_gt   (1,N,3)
    const float* coords = (const float*)d_in[2];  // (N,3)
    const int*   ksm    = (const int*)d_in[3];    // smoothness_k (=9)

    float* ws    = (float*)d_ws;
    float* pc2   = ws;                 // 3N
    float* warp  = ws + 3 * N_PTS;     // 3N
    float* curv2 = ws + 6 * N_PTS;     // 3N
    float* mcurv = ws + 9 * N_PTS;     // 3N
    float* accs  = ws + 12 * N_PTS;    // [dist1, dist2, smooth, curv]
    float* out   = (float*)d_out;

    prep_kernel<<<(3 * N_PTS + 255) / 256, 256, 0, stream>>>(flow, gt, coords, pc2, warp, accs);
    curv2_kernel<<<N_PTS / QPB, 256, 0, stream>>>(pc2, curv2);
    pc1_kernel<<<N_PTS / QPB, 256, 0, stream>>>(coords, warp, flow, ksm, mcurv, accs);
    cross_kernel<<<N_PTS / QPB, 256, 0, stream>>>(warp, pc2, curv2, mcurv, accs);
    rev_kernel<<<N_PTS / QPB, 256, 0, stream>>>(pc2, warp, accs);
    fin_kernel<<<1, 64, 0, stream>>>(accs, out);
}